// Round 4
// baseline (270.645 us; speedup 1.0000x reference)
//
#include <hip/hip_runtime.h>
#include <hip/hip_bf16.h>

// FlowNetC correlation via bf16 MFMA band-GEMM, register-pipelined staging.
// out[b, (dy+4)*9+(dx+4), y, x] = (1/256) * sum_c in1[b,c,y,x] * in2[b,c,y+dy,x+dx]
// B=8, C=256, H=96, W=128, MD=4.
//
// Block = (b, 4-row y-tile, 32-px x-quarter), 1024 threads (16 waves).
// Grid = 8*24*4 = 768 = 3 balanced rounds on 256 CUs.
// Chunk = 32 channels; LDS single buffer: in1 4x32 px + in2 12x48 px (halo),
// 64 B/px-slot, 704 slots = 44 KB. Staging loads for chunk k+1 are issued
// before chunk k's MFMA phase and consumed after the next barrier.
// Wave = (xt, ut, yp): 2 x-subtiles x 2 u-tiles x 4 single rows.
// acc = 9 f32x4 = 36 VGPRs -> with 32 prefetch regs stays under 128.

#define H_ 96
#define W_ 128
#define HW_ 12288
#define CHW_ 3145728

#define IN2OFF (128 * 64)            // in1: 128 slots, then in2: 576 slots
#define LDS_BYTES (704 * 64)         // 45056

typedef __attribute__((ext_vector_type(8))) short short8;
typedef __attribute__((ext_vector_type(4))) float f32x4;

// group placement swizzle: group g of pixel-slot p lives at (g ^ (p&3) ^ ((p>>2)&3))*16
__device__ __forceinline__ int grpswz(int g, int p) {
    return ((g ^ (p & 3) ^ ((p >> 2) & 3)) & 3) * 16;
}

__global__ __launch_bounds__(1024, 4) void corr_mfma3(
    const float* __restrict__ in1,
    const float* __restrict__ in2,
    float* __restrict__ out)
{
    __shared__ __align__(16) char lds[LDS_BYTES];

    const int tid = threadIdx.x;
    const int blk = blockIdx.x;
    const int b   = blk & 7;             // XCD-affine batch
    const int i   = blk >> 3;            // 0..95, consecutive i share y-window
    const int yt  = i >> 2;              // 0..23 (4-row tiles)
    const int xq  = i & 3;               // 0..3  (32-px quarters)

    // ---- staging role: unit = 4 px x 8 ch ----
    const bool stager = (tid < 704);
    const float* gbase = nullptr;        // unit's base ptr (chunk 0)
    bool valid = false;
    int lds_dst0 = 0;                    // byte addr of slot p0, group key precomputed
    int kk = 0;                          // g ^ (q&3): swizzle key base
    if (stager) {
        if (tid < 576) {                 // in2: 144 px-quads x 4 groups
            const int pq = tid % 144;
            const int g  = tid / 144;            // 0..3
            const int r  = pq / 12;              // 0..11
            const int q  = pq % 12;              // px-quad in row
            const int gx = xq * 32 - 8 + 4 * q;
            const int ry = yt * 4 - 4 + r;
            valid = (ry >= 0) && (ry < H_) && (gx >= 0) && (gx <= W_ - 4);
            gbase = in2 + (size_t)b * CHW_ + (size_t)(8 * g) * HW_ + ry * W_ + gx;
            lds_dst0 = IN2OFF + (r * 48 + 4 * q) * 64;
            kk = g ^ (q & 3);
        } else {                         // in1: 32 px-quads x 4 groups
            const int u1 = tid - 576;
            const int pq = u1 % 32;
            const int g  = u1 / 32;
            const int r  = pq / 8;               // 0..3
            const int q  = pq % 8;
            const int gx = xq * 32 + 4 * q;
            const int yy = yt * 4 + r;
            valid = true;
            gbase = in1 + (size_t)b * CHW_ + (size_t)(8 * g) * HW_ + yy * W_ + gx;
            lds_dst0 = (r * 32 + 4 * q) * 64;
            kk = g ^ (q & 3);
        }
    }

    // ---- compute ids ----
    const int lane = tid & 63;
    const int wv   = tid >> 6;           // 0..15
    const int xt   = wv & 1;
    const int ut   = (wv >> 1) & 1;
    const int yp   = wv >> 2;            // 0..3 -> row yt*4 + yp
    const int ln   = lane & 15;
    const int qd   = lane >> 4;

    const int pA   = 16 * xt + ln;                               // 0..31
    const int offA = (yp * 32 + pA) * 64 + grpswz(qd, pA);
    const int pB   = 16 * (xt + ut) + ln;                        // 0..47
    const int offB = IN2OFF + (yp * 48 + pB) * 64 + grpswz(qd, pB);

    f32x4 acc[9];
    #pragma unroll
    for (int s = 0; s < 9; ++s) acc[s] = f32x4{0.f, 0.f, 0.f, 0.f};

    // ---- prologue: load chunk 0 into regs ----
    float4 pf[8];
    #pragma unroll
    for (int j = 0; j < 8; ++j) pf[j] = float4{0.f, 0.f, 0.f, 0.f};
    if (stager && valid) {
        #pragma unroll
        for (int j = 0; j < 8; ++j) pf[j] = *(const float4*)(gbase + (size_t)j * HW_);
    }

    #pragma unroll
    for (int kc = 0; kc < 8; ++kc) {
        if (kc > 0) __syncthreads();     // prior frag reads done before overwrite
        // ---- regs -> LDS (bf16) ----
        if (stager) {
            #pragma unroll
            for (int px = 0; px < 4; ++px) {
                union { __hip_bfloat162 h2[4]; short8 s8; } u;
                #pragma unroll
                for (int jj = 0; jj < 4; ++jj) {
                    float2 f;
                    f.x = ((const float*)&pf[2 * jj])[px];
                    f.y = ((const float*)&pf[2 * jj + 1])[px];
                    u.h2[jj] = __float22bfloat162_rn(f);
                }
                *(short8*)(lds + lds_dst0 + px * 64 + ((kk ^ px) & 3) * 16) = u.s8;
            }
        }
        __syncthreads();
        // ---- issue next chunk's global loads (consumed next iteration) ----
        if (kc < 7 && stager) {
            const float* g2 = gbase + (size_t)(32 * (kc + 1)) * HW_;
            #pragma unroll
            for (int j = 0; j < 8; ++j)
                pf[j] = valid ? *(const float4*)(g2 + (size_t)j * HW_)
                              : float4{0.f, 0.f, 0.f, 0.f};
        }
        // ---- MFMA phase: 1 A-frag + 9 B-frags ----
        short8 afr = *(const short8*)(lds + offA);
        #pragma unroll
        for (int s = 0; s < 9; ++s) {
            short8 bfr = *(const short8*)(lds + offB + s * (48 * 64));
            acc[s] = __builtin_amdgcn_mfma_f32_16x16x32_bf16(afr, bfr, acc[s], 0, 0, 0);
        }
    }

    // ---- epilogue: band extraction ----
    // D: col n = ln -> u = xq*32 - 8 + 16*(xt+ut) + ln; row m = qd*4+r -> x = x0+m
    const float scale = 1.0f / 256.0f;
    const int x0 = xq * 32 + 16 * xt;
    const int y  = yt * 4 + yp;
    #pragma unroll
    for (int s = 0; s < 9; ++s) {
        #pragma unroll
        for (int r = 0; r < 4; ++r) {
            const int m  = qd * 4 + r;
            const int dx = ln - m - 8 + 16 * ut;
            if (dx >= -4 && dx <= 4) {
                out[(((size_t)b * 81 + (size_t)(s * 9 + dx + 4)) * H_ + y) * W_ + (x0 + m)]
                    = acc[s][r] * scale;
            }
        }
    }
}

extern "C" void kernel_launch(void* const* d_in, const int* in_sizes, int n_in,
                              void* d_out, int out_size, void* d_ws, size_t ws_size,
                              hipStream_t stream) {
    const float* in1 = (const float*)d_in[0];
    const float* in2 = (const float*)d_in[1];
    float* out = (float*)d_out;

    // 8 b x 24 y-tiles x 4 x-quarters = 768 blocks (3 balanced rounds)
    corr_mfma3<<<768, 1024, 0, stream>>>(in1, in2, out);
}